// Round 2
// baseline (97.573 us; speedup 1.0000x reference)
//
#include <hip/hip_runtime.h>
#include <hip/hip_bf16.h>

#define MM 128      // molecules
#define NA 21       // atoms
#define DD 210      // descriptors
#define DP 224      // padded descriptors (multiple of 32)
#define TT 4096     // training points

#define QF   0.22360679774997896f   // sqrt(5)/10
#define Q2F  0.05f                  // Q^2 = 5/100
#define K0E  0.016666666666666666f  // 5/(3*SIG^2) = 1/60
#define INVQ 4.47213595499958f      // 1/Q

// ---- workspace layout (float offsets) ----
#define OFF_TRP 0                       // [TT][DP]
#define OFF_JXP (OFF_TRP + TT*DP)       // [TT][DP]
#define OFF_W1  (OFF_JXP + TT*DP)       // [MM][TT]
#define OFF_W2  (OFF_W1 + MM*TT)        // [MM][TT]
#define OFF_XSP (OFF_W2 + MM*TT)        // [MM][DP]
#define OFF_NT  (OFF_XSP + MM*DP)       // [TT]
#define OFF_CT  (OFF_NT + TT)           // [TT]
#define OFF_NM  (OFF_CT + TT)           // [MM]
#define OFF_A1  (OFF_NM + MM)           // [MM][DP]  (zero-init)
#define OFF_A2  (OFF_A1 + MM*DP)        // [MM][DP]  (zero-init)
#define OFF_S1  (OFF_A2 + MM*DP)        // [MM]      (zero-init)
#define OFF_E   (OFF_S1 + MM)           // [MM]      (zero-init)
#define ZERO_FLOATS (MM*DP*2 + MM*2)

// ---------- K0: pad/copy xs_train and Jx_alphas to stride DP ----------
__global__ __launch_bounds__(256) void k0_pad(const float* __restrict__ tr,
                                              const float* __restrict__ jx,
                                              float* __restrict__ trp,
                                              float* __restrict__ jxp) {
    int idx = blockIdx.x * 256 + threadIdx.x;
    if (idx >= TT * DP) return;
    int row = idx / DP, col = idx - row * DP;
    float v1 = 0.f, v2 = 0.f;
    if (col < DD) { v1 = tr[row * DD + col]; v2 = jx[row * DD + col]; }
    trp[idx] = v1; jxp[idx] = v2;
}

// ---------- K0b: per-training-point norms nt=|xt|^2, ct=xt.Jx ----------
// DP=224 = 3.5 * 64 -> 3 full chunks + one half-masked chunk (fixes OOB read)
__global__ __launch_bounds__(256) void k0b_ntct(const float* __restrict__ trp,
                                                const float* __restrict__ jxp,
                                                float* __restrict__ nt,
                                                float* __restrict__ ct) {
    int t = blockIdx.x * 4 + (threadIdx.x >> 6);
    int l = threadIdx.x & 63;
    float sn = 0.f, sc = 0.f;
    #pragma unroll
    for (int k = 0; k < 3; ++k) {
        int id = t * DP + l + k * 64;
        float v1 = trp[id];
        float v2 = jxp[id];
        sn = fmaf(v1, v1, sn);
        sc = fmaf(v1, v2, sc);
    }
    if (l < 32) {
        int id = t * DP + 192 + l;
        float v1 = trp[id];
        float v2 = jxp[id];
        sn = fmaf(v1, v1, sn);
        sc = fmaf(v1, v2, sc);
    }
    #pragma unroll
    for (int off = 32; off >= 1; off >>= 1) {
        sn += __shfl_xor(sn, off);
        sc += __shfl_xor(sc, off);
    }
    if (l == 0) { nt[t] = sn; ct[t] = sc; }
}

// ---------- K1: descriptors xs[m,d] = 1/dist(pair d), nm=|xs|^2 ----------
__global__ __launch_bounds__(256) void k1_xs(const float* __restrict__ Rs,
                                             float* __restrict__ xsp,
                                             float* __restrict__ nmg) {
    int m = blockIdx.x, tid = threadIdx.x;
    __shared__ float Rl[64];
    __shared__ float red[4];
    if (tid < NA * 3) Rl[tid] = Rs[m * NA * 3 + tid];
    __syncthreads();
    float v = 0.f;
    if (tid < DP) {
        float x = 0.f;
        if (tid < DD) {
            int d = tid;
            int a = (int)((1.0f + sqrtf(8.0f * (float)d + 1.0f)) * 0.5f);
            while (a * (a - 1) / 2 > d) --a;
            while ((a + 1) * a / 2 <= d) ++a;
            int b = d - a * (a - 1) / 2;
            float dx = Rl[a * 3 + 0] - Rl[b * 3 + 0];
            float dy = Rl[a * 3 + 1] - Rl[b * 3 + 1];
            float dz = Rl[a * 3 + 2] - Rl[b * 3 + 2];
            x = 1.0f / sqrtf(dx * dx + dy * dy + dz * dz);
        }
        xsp[m * DP + tid] = x;   // pad cols -> 0
        v = x * x;
    }
    #pragma unroll
    for (int off = 32; off >= 1; off >>= 1) v += __shfl_xor(v, off);
    if ((tid & 63) == 0) red[tid >> 6] = v;
    __syncthreads();
    if (tid == 0) nmg[m] = red[0] + red[1] + red[2] + red[3];
}

// ---------- K2: phase A -- G1/G2 tiles -> W1,W2, s1, E ----------
// tile: BM=32 (m) x BT=64 (t), BD=32 k-chunk, 128 threads, micro 4m x 4t
#define BM 32
#define BT 64
#define BD 32
__global__ __launch_bounds__(128) void k2_phaseA(
        const float* __restrict__ xsp, const float* __restrict__ trp,
        const float* __restrict__ jxp, const float* __restrict__ nm,
        const float* __restrict__ nt, const float* __restrict__ ct,
        float* __restrict__ W1, float* __restrict__ W2,
        float* __restrict__ s1g, float* __restrict__ Eg) {
    __shared__ __align__(16) float As[BD][BM + 4];   // stride 36
    __shared__ __align__(16) float Ts[BD][BT + 4];   // stride 68
    __shared__ __align__(16) float Js[BD][BT + 4];
    int tid = threadIdx.x;
    int t0 = blockIdx.x * BT;
    int m0 = blockIdx.y * BM;
    int ty = tid >> 4;      // 0..7 -> m micro row * 4
    int tx = tid & 15;      // 0..15 -> t micro col * 4
    float g1[4][4] = {{0.f}};
    float g2[4][4] = {{0.f}};
    int amm = tid >> 2;     // 0..31
    int aseg = tid & 3;     // 0..3  -> 8 cols
    int ttt = tid >> 1;     // 0..63
    int tseg = tid & 1;     // 0..1  -> 16 cols

    for (int dk = 0; dk < DP; dk += BD) {
        const float* ap = xsp + (m0 + amm) * DP + dk + aseg * 8;
        float4 av0 = *(const float4*)(ap);
        float4 av1 = *(const float4*)(ap + 4);
        const float* tp = trp + (t0 + ttt) * DP + dk + tseg * 16;
        const float* jp = jxp + (t0 + ttt) * DP + dk + tseg * 16;
        float4 tv0 = *(const float4*)(tp);
        float4 tv1 = *(const float4*)(tp + 4);
        float4 tv2 = *(const float4*)(tp + 8);
        float4 tv3 = *(const float4*)(tp + 12);
        float4 jv0 = *(const float4*)(jp);
        float4 jv1 = *(const float4*)(jp + 4);
        float4 jv2 = *(const float4*)(jp + 8);
        float4 jv3 = *(const float4*)(jp + 12);
        __syncthreads();
        As[aseg * 8 + 0][amm] = av0.x; As[aseg * 8 + 1][amm] = av0.y;
        As[aseg * 8 + 2][amm] = av0.z; As[aseg * 8 + 3][amm] = av0.w;
        As[aseg * 8 + 4][amm] = av1.x; As[aseg * 8 + 5][amm] = av1.y;
        As[aseg * 8 + 6][amm] = av1.z; As[aseg * 8 + 7][amm] = av1.w;
        int c0 = tseg * 16;
        Ts[c0 + 0][ttt] = tv0.x;  Ts[c0 + 1][ttt] = tv0.y;  Ts[c0 + 2][ttt] = tv0.z;  Ts[c0 + 3][ttt] = tv0.w;
        Ts[c0 + 4][ttt] = tv1.x;  Ts[c0 + 5][ttt] = tv1.y;  Ts[c0 + 6][ttt] = tv1.z;  Ts[c0 + 7][ttt] = tv1.w;
        Ts[c0 + 8][ttt] = tv2.x;  Ts[c0 + 9][ttt] = tv2.y;  Ts[c0 + 10][ttt] = tv2.z; Ts[c0 + 11][ttt] = tv2.w;
        Ts[c0 + 12][ttt] = tv3.x; Ts[c0 + 13][ttt] = tv3.y; Ts[c0 + 14][ttt] = tv3.z; Ts[c0 + 15][ttt] = tv3.w;
        Js[c0 + 0][ttt] = jv0.x;  Js[c0 + 1][ttt] = jv0.y;  Js[c0 + 2][ttt] = jv0.z;  Js[c0 + 3][ttt] = jv0.w;
        Js[c0 + 4][ttt] = jv1.x;  Js[c0 + 5][ttt] = jv1.y;  Js[c0 + 6][ttt] = jv1.z;  Js[c0 + 7][ttt] = jv1.w;
        Js[c0 + 8][ttt] = jv2.x;  Js[c0 + 9][ttt] = jv2.y;  Js[c0 + 10][ttt] = jv2.z; Js[c0 + 11][ttt] = jv2.w;
        Js[c0 + 12][ttt] = jv3.x; Js[c0 + 13][ttt] = jv3.y; Js[c0 + 14][ttt] = jv3.z; Js[c0 + 15][ttt] = jv3.w;
        __syncthreads();
        #pragma unroll
        for (int dd = 0; dd < BD; ++dd) {
            float4 a  = *(const float4*)&As[dd][ty * 4];
            float4 tv = *(const float4*)&Ts[dd][tx * 4];
            float4 jv = *(const float4*)&Js[dd][tx * 4];
            float am[4] = {a.x, a.y, a.z, a.w};
            float t4[4] = {tv.x, tv.y, tv.z, tv.w};
            float j4[4] = {jv.x, jv.y, jv.z, jv.w};
            #pragma unroll
            for (int i = 0; i < 4; ++i) {
                #pragma unroll
                for (int k = 0; k < 4; ++k) {
                    g1[i][k] = fmaf(am[i], t4[k], g1[i][k]);
                    g2[i][k] = fmaf(am[i], j4[k], g2[i][k]);
                }
            }
        }
    }

    float nmv[4], ntv[4], ctv[4];
    #pragma unroll
    for (int i = 0; i < 4; ++i) nmv[i] = nm[m0 + ty * 4 + i];
    #pragma unroll
    for (int k = 0; k < 4; ++k) { ntv[k] = nt[t0 + tx * 4 + k]; ctv[k] = ct[t0 + tx * 4 + k]; }

    float s1loc[4] = {0.f, 0.f, 0.f, 0.f};
    float eloc[4]  = {0.f, 0.f, 0.f, 0.f};
    #pragma unroll
    for (int i = 0; i < 4; ++i) {
        float w1v[4], w2v[4];
        #pragma unroll
        for (int k = 0; k < 4; ++k) {
            float d2 = Q2F * (nmv[i] + ntv[k] - 2.f * g1[i][k]);
            float xd = sqrtf(fmaxf(d2, 0.f));
            float e  = K0E * __expf(-xd);
            float dv = QF * (g2[i][k] - ctv[k]);
            float w1 = e * dv;
            float w2 = e * (1.f + xd);
            w1v[k] = w1; w2v[k] = w2;
            s1loc[i] += w1;
            eloc[i]  = fmaf(w2, dv, eloc[i]);
        }
        float4 o1 = {w1v[0], w1v[1], w1v[2], w1v[3]};
        float4 o2 = {w2v[0], w2v[1], w2v[2], w2v[3]};
        *(float4*)&W1[(m0 + ty * 4 + i) * TT + t0 + tx * 4] = o1;
        *(float4*)&W2[(m0 + ty * 4 + i) * TT + t0 + tx * 4] = o2;
    }
    #pragma unroll
    for (int off = 8; off >= 1; off >>= 1) {
        #pragma unroll
        for (int i = 0; i < 4; ++i) {
            s1loc[i] += __shfl_xor(s1loc[i], off);
            eloc[i]  += __shfl_xor(eloc[i], off);
        }
    }
    if (tx == 0) {
        #pragma unroll
        for (int i = 0; i < 4; ++i) {
            atomicAdd(&s1g[m0 + ty * 4 + i], s1loc[i]);
            atomicAdd(&Eg[m0 + ty * 4 + i], eloc[i]);
        }
    }
}

// ---------- K3: phase B -- A1 = W1 @ trp, A2 = W2 @ jxp (split over T) ----------
__global__ __launch_bounds__(256) void k3_phaseB(
        const float* __restrict__ W1, const float* __restrict__ W2,
        const float* __restrict__ trp, const float* __restrict__ jxp,
        float* __restrict__ A1, float* __restrict__ A2) {
    int tid = threadIdx.x;
    int t0 = blockIdx.x * 128;
    int m0 = blockIdx.y * 8;
    if (tid >= DP) return;
    float acc1[8] = {0.f, 0.f, 0.f, 0.f, 0.f, 0.f, 0.f, 0.f};
    float acc2[8] = {0.f, 0.f, 0.f, 0.f, 0.f, 0.f, 0.f, 0.f};
    for (int t = 0; t < 128; ++t) {
        float v1 = trp[(t0 + t) * DP + tid];
        float v2 = jxp[(t0 + t) * DP + tid];
        int wb = t0 + t;
        #pragma unroll
        for (int mi = 0; mi < 8; ++mi) {
            acc1[mi] = fmaf(W1[(m0 + mi) * TT + wb], v1, acc1[mi]);
            acc2[mi] = fmaf(W2[(m0 + mi) * TT + wb], v2, acc2[mi]);
        }
    }
    #pragma unroll
    for (int mi = 0; mi < 8; ++mi) {
        atomicAdd(&A1[(m0 + mi) * DP + tid], acc1[mi]);
        atomicAdd(&A2[(m0 + mi) * DP + tid], acc2[mi]);
    }
}

// ---------- K4: final forces + energies ----------
__global__ __launch_bounds__(256) void k4_final(
        const float* __restrict__ Rs, const float* __restrict__ xsp,
        const float* __restrict__ A1, const float* __restrict__ A2,
        const float* __restrict__ s1g, const float* __restrict__ Eg,
        float* __restrict__ out) {
    int m = blockIdx.x, tid = threadIdx.x;
    __shared__ float fxs[DD];
    __shared__ float Rl[64];
    if (tid < NA * 3) Rl[tid] = Rs[m * NA * 3 + tid];
    float s1v = s1g[m];
    if (tid < DD)
        fxs[tid] = QF * xsp[m * DP + tid] * s1v - QF * A1[m * DP + tid] - A2[m * DP + tid];
    __syncthreads();
    if (tid < NA * 3) {
        int b = tid / 3, c = tid - b * 3;
        float acc = 0.f;
        #pragma unroll
        for (int a = 0; a < NA; ++a) {
            if (a == b) continue;
            int hi = a > b ? a : b, lo = a > b ? b : a;
            int d = hi * (hi - 1) / 2 + lo;
            float dx = Rl[a * 3 + 0] - Rl[b * 3 + 0];
            float dy = Rl[a * 3 + 1] - Rl[b * 3 + 1];
            float dz = Rl[a * 3 + 2] - Rl[b * 3 + 2];
            float r2 = dx * dx + dy * dy + dz * dz;
            float ir = 1.0f / sqrtf(r2);
            float w = fxs[d] * ir * ir * ir;
            float comp = (c == 0) ? dx : ((c == 1) ? dy : dz);
            acc = fmaf(w, comp, acc);
        }
        out[MM + m * NA * 3 + tid] = acc;
    }
    if (tid == 64) out[m] = Eg[m] * INVQ;
}

extern "C" void kernel_launch(void* const* d_in, const int* in_sizes, int n_in,
                              void* d_out, int out_size, void* d_ws, size_t ws_size,
                              hipStream_t stream) {
    const float* Rs = (const float*)d_in[0];
    const float* tr = (const float*)d_in[1];
    const float* jx = (const float*)d_in[2];
    float* out = (float*)d_out;
    float* ws = (float*)d_ws;

    float* trp = ws + OFF_TRP;
    float* jxp = ws + OFF_JXP;
    float* W1  = ws + OFF_W1;
    float* W2  = ws + OFF_W2;
    float* xsp = ws + OFF_XSP;
    float* nt  = ws + OFF_NT;
    float* ct  = ws + OFF_CT;
    float* nm  = ws + OFF_NM;
    float* A1  = ws + OFF_A1;
    float* A2  = ws + OFF_A2;
    float* s1  = ws + OFF_S1;
    float* Eg  = ws + OFF_E;

    hipMemsetAsync(ws + OFF_A1, 0, (size_t)ZERO_FLOATS * sizeof(float), stream);
    k0_pad<<<(TT * DP + 255) / 256, 256, 0, stream>>>(tr, jx, trp, jxp);
    k0b_ntct<<<TT / 4, 256, 0, stream>>>(trp, jxp, nt, ct);
    k1_xs<<<MM, 256, 0, stream>>>(Rs, xsp, nm);
    k2_phaseA<<<dim3(TT / BT, MM / BM), 128, 0, stream>>>(xsp, trp, jxp, nm, nt, ct, W1, W2, s1, Eg);
    k3_phaseB<<<dim3(TT / 128, MM / 8), 256, 0, stream>>>(W1, W2, trp, jxp, A1, A2);
    k4_final<<<MM, 256, 0, stream>>>(Rs, xsp, A1, A2, s1, Eg, out);
}